// Round 5
// baseline (261.846 us; speedup 1.0000x reference)
//
#include <hip/hip_runtime.h>
#include <math.h>

#define B_ 4
#define S_ 2048
#define D_ 512
#define H_ 8
#define HD_ 64
#define RL_ 64
#define LN_EPS 1e-5f
#define SLOPE 0.01f
#define LOG2E 1.4426950408889634f

typedef __attribute__((ext_vector_type(8))) __bf16 bf16x8;
typedef __attribute__((ext_vector_type(4))) float f32x4;

__device__ __forceinline__ float leaky(float x) { return x >= 0.f ? x : SLOPE * x; }

// float -> bf16 (RNE)
__device__ __forceinline__ ushort f2bf(float f) {
    union { float f; unsigned u; } v; v.f = f;
    unsigned r = v.u + 0x7fffu + ((v.u >> 16) & 1u);
    return (ushort)(r >> 16);
}

__device__ __forceinline__ void g2lds16(const void* g, void* l) {
    __builtin_amdgcn_global_load_lds(
        (const __attribute__((address_space(1))) void*)(uintptr_t)g,
        (__attribute__((address_space(3))) void*)(uintptr_t)l, 16, 0, 0);
}

// ---------------------------------------------------------------------------
// casts
// ---------------------------------------------------------------------------
__global__ __launch_bounds__(256) void cast4(const float* __restrict__ in,
                                             ushort* __restrict__ out) {
    const int i = blockIdx.x * 256 + threadIdx.x;
    const float4 v = ((const float4*)in)[i];
    ushort4 o; o.x = f2bf(v.x); o.y = f2bf(v.y); o.z = f2bf(v.z); o.w = f2bf(v.w);
    ((ushort4*)out)[i] = o;
}

// in [K][512] f32 -> out [512][K] bf16
__global__ __launch_bounds__(256) void tcast(const float* __restrict__ in,
                                             ushort* __restrict__ out,
                                             int K, int logK) {
    const int idx = blockIdx.x * 256 + threadIdx.x;
    const int k = idx & (K - 1), n = idx >> logK;
    out[idx] = f2bf(in[k * 512 + n]);
}

// ---------------------------------------------------------------------------
// MFMA GEMM: C[M,512] = A[M,K]bf16 @ W (WT[512,K] bf16, n-major).
// 64x128 tile -> 512 blocks (2/CU). 4 waves in 2x2 (wave = 32m x 64n).
// global_load_lds staging, chunk-swizzled unpadded LDS (2-way max = free).
// MODE 0: fp32 store C[M,512]
// MODE 2: frT[b,h,d,s] bf16 store + sred = scale * sum_d leaky(c)*avec[d]
// MODE 3: bf16 store [b,h,s,64] scaled; gridDim.z=2 selects (WT,Cout,scale)
//         vs (WT2,Cout2,scale2) — the two relation projections fused.
// ---------------------------------------------------------------------------
template <int MODE>
__global__ __launch_bounds__(256) void mfma_gemm(
    const ushort* __restrict__ A, const ushort* __restrict__ WT,
    void* __restrict__ Cout, float* __restrict__ sred,
    const float* __restrict__ avec, int K, float scale,
    const ushort* __restrict__ WT2, void* __restrict__ Cout2, float scale2)
{
    __shared__ ushort As[64 * 32];    // 4 KB
    __shared__ ushort Bs[128 * 32];   // 8 KB

    const int tid = threadIdx.x;
    const int lane = tid & 63, w = tid >> 6;
    const int ln = lane & 15, quad = lane >> 4;
    const int wm = w >> 1, wn = w & 1;
    const int m0 = blockIdx.x * 64, n0 = blockIdx.y * 128;

    const ushort* wt = WT; void* co = Cout; float scl = scale;
    if constexpr (MODE == 3) {
        if (blockIdx.z) { wt = WT2; co = Cout2; scl = scale2; }
    }

    // A staging: row = tid>>2 (64 rows), phys chunk = lane&3; LDS = tid*16B
    const int srA = tid >> 2;
    const int lchA = ((lane & 3) - (srA >> 1)) & 3;
    const ushort* Ag = A + (size_t)(m0 + srA) * K + lchA * 8;
    ushort* AsL = As + (size_t)tid * 8;
    // B staging: rows w*32+(lane>>2) and +16 (same lchunk: +16 rows ≡ 0 mod 4)
    const int srB = w * 32 + (lane >> 2);
    const int lchB = ((lane & 3) - (srB >> 1)) & 3;
    const ushort* Bg0 = wt + (size_t)(n0 + srB) * K + lchB * 8;
    const ushort* Bg1 = Bg0 + (size_t)16 * K;
    ushort* BsL = Bs + srB * 32 + (lane & 3) * 8;

    const int pc = (quad + (ln >> 1)) & 3;   // frag-read physical chunk

    f32x4 acc[2][4] = {};
    for (int k0 = 0; k0 < K; k0 += 32) {
        __syncthreads();
        g2lds16(Ag, AsL);
        g2lds16(Bg0, BsL); g2lds16(Bg1, BsL + 512);
        Ag += 32; Bg0 += 32; Bg1 += 32;
        __syncthreads();

        bf16x8 af[2], bfr[4];
        #pragma unroll
        for (int mi = 0; mi < 2; ++mi)
            af[mi] = *(const bf16x8*)&As[(wm * 32 + mi * 16 + ln) * 32 + pc * 8];
        #pragma unroll
        for (int ni = 0; ni < 4; ++ni)
            bfr[ni] = *(const bf16x8*)&Bs[(wn * 64 + ni * 16 + ln) * 32 + pc * 8];
        #pragma unroll
        for (int mi = 0; mi < 2; ++mi)
            #pragma unroll
            for (int ni = 0; ni < 4; ++ni)
                acc[mi][ni] = __builtin_amdgcn_mfma_f32_16x16x32_bf16(
                    af[mi], bfr[ni], acc[mi][ni], 0, 0, 0);
    }

    // epilogue: row = m0 + wm*32 + mi*16 + quad*4 + r ; col = n0 + wn*64 + ni*16 + ln
    if constexpr (MODE == 0) {
        float* C = (float*)co;
        #pragma unroll
        for (int mi = 0; mi < 2; ++mi) {
            const int row = m0 + wm * 32 + mi * 16 + quad * 4;
            #pragma unroll
            for (int ni = 0; ni < 4; ++ni) {
                const int col = n0 + wn * 64 + ni * 16 + ln;
                #pragma unroll
                for (int r = 0; r < 4; ++r)
                    C[(size_t)(row + r) * 512 + col] = acc[mi][ni][r];
            }
        }
    }
    if constexpr (MODE == 2 || MODE == 3) {
        const int head = blockIdx.y * 2 + wn;
        const int b = m0 >> 11;
        const size_t bh = (size_t)b * H_ + head;
        if constexpr (MODE == 2) {
            ushort* frT = (ushort*)co;
            #pragma unroll
            for (int mi = 0; mi < 2; ++mi) {
                const int s = (m0 & (S_ - 1)) + wm * 32 + mi * 16 + quad * 4;
                #pragma unroll
                for (int ni = 0; ni < 4; ++ni) {
                    const int d = ni * 16 + ln;
                    ushort4 o;
                    o.x = f2bf(acc[mi][ni][0]); o.y = f2bf(acc[mi][ni][1]);
                    o.z = f2bf(acc[mi][ni][2]); o.w = f2bf(acc[mi][ni][3]);
                    *(ushort4*)(frT + (bh * 64 + d) * S_ + s) = o;
                }
            }
            float a4[4];
            #pragma unroll
            for (int ni = 0; ni < 4; ++ni) a4[ni] = avec[ni * 16 + ln];
            #pragma unroll
            for (int mi = 0; mi < 2; ++mi) {
                const int s = (m0 & (S_ - 1)) + wm * 32 + mi * 16 + quad * 4;
                #pragma unroll
                for (int r = 0; r < 4; ++r) {
                    float v = 0.f;
                    #pragma unroll
                    for (int ni = 0; ni < 4; ++ni)
                        v += leaky(acc[mi][ni][r]) * a4[ni];
                    #pragma unroll
                    for (int off = 8; off; off >>= 1) v += __shfl_xor(v, off, 16);
                    if (ln == 0) sred[bh * S_ + s + r] = v * scl;
                }
            }
        }
        if constexpr (MODE == 3) {
            ushort* O = (ushort*)co;
            #pragma unroll
            for (int mi = 0; mi < 2; ++mi) {
                const int s = (m0 & (S_ - 1)) + wm * 32 + mi * 16 + quad * 4;
                #pragma unroll
                for (int ni = 0; ni < 4; ++ni) {
                    const int d = ni * 16 + ln;
                    #pragma unroll
                    for (int r = 0; r < 4; ++r)
                        O[(bh * S_ + s + r) * 64 + d] = f2bf(acc[mi][ni][r] * scl);
                }
            }
        }
    }
}

// ---------------------------------------------------------------------------
// Flash attention, bf16 MFMA, barrier-free K-loop. 4 waves x 32 q per block
// (grid 16x8x4 = 512 blocks). B-fragments (rq, frT) loaded DIRECTLY from
// global (L2-resident: 512 KB/bh reused by 16 q-blocks) — no LDS staging,
// no per-tile __syncthreads. Only per-wave P-strips round-trip through LDS
// (C-layout write -> A-layout b128 read; wave-internal, R2/R4-proven).
// No max-subtraction (scores pre-scaled by LOG2E, bounded); sl cancels.
// ---------------------------------------------------------------------------
__global__ __launch_bounds__(256) void attn_mfma(
    const ushort* __restrict__ frT, const ushort* __restrict__ rk,
    const ushort* __restrict__ rq, const float* __restrict__ sr,
    ushort* __restrict__ hsa)
{
    __shared__ float SRs[S_];          // 8 KB
    __shared__ ushort PS[8][16][72];   // 18 KB: per-(wave,qs) P strips

    const int tid = threadIdx.x;
    const int w = tid >> 6;
    const int lane = tid & 63;
    const int ln = lane & 15;
    const int quad = lane >> 4;
    const int b = blockIdx.z, h = blockIdx.y, q0 = blockIdx.x * 128;
    const size_t bh = (size_t)b * H_ + h;

    for (int i = tid; i < S_; i += 256) SRs[i] = sr[bh * S_ + i];
    __syncthreads();   // the only barrier

    // A-frags (rk), 2 q-sets of 16: A[m=ln][k=quad*8+j (+32)]
    const ushort* rkb = rk + ((bh * S_ + q0 + w * 32) << 6);
    bf16x8 a[2][2];
    #pragma unroll
    for (int qs = 0; qs < 2; ++qs) {
        const ushort* p = rkb + (qs * 16 + ln) * 64 + quad * 8;
        a[qs][0] = *(const bf16x8*)p;
        a[qs][1] = *(const bf16x8*)(p + 32);
    }

    float lsum[2][4] = {};
    f32x4 ctx[2][4] = {};

    const ushort* rqb = rq + (bh * S_ << 6);
    const ushort* ftb = frT + (size_t)bh * 64 * S_;

    for (int t0 = 0; t0 < S_; t0 += 64) {
        // QK^T B-frags from global: B[k=r][n=t], row t0+16jb+ln
        bf16x8 qb0[4], qb1[4];
        #pragma unroll
        for (int jb = 0; jb < 4; ++jb) {
            const ushort* p = rqb + ((size_t)(t0 + 16 * jb + ln) << 6) + quad * 8;
            qb0[jb] = *(const bf16x8*)p;
            qb1[jb] = *(const bf16x8*)(p + 32);
        }
        f32x4 sc[2][4];
        #pragma unroll
        for (int qs = 0; qs < 2; ++qs)
            #pragma unroll
            for (int jb = 0; jb < 4; ++jb) {
                f32x4 t = {0.f, 0.f, 0.f, 0.f};
                t = __builtin_amdgcn_mfma_f32_16x16x32_bf16(a[qs][0], qb0[jb], t, 0, 0, 0);
                t = __builtin_amdgcn_mfma_f32_16x16x32_bf16(a[qs][1], qb1[jb], t, 0, 0, 0);
                sc[qs][jb] = t;
            }

        float srv[4];
        #pragma unroll
        for (int jb = 0; jb < 4; ++jb) srv[jb] = SRs[t0 + 16 * jb + ln];

        // softmax (exp2, no max) -> P strips
        #pragma unroll
        for (int qs = 0; qs < 2; ++qs)
            #pragma unroll
            for (int r = 0; r < 4; ++r) {
                const int prow = quad * 4 + r;
                float psum = 0.f;
                #pragma unroll
                for (int jb = 0; jb < 4; ++jb) {
                    const float p = __builtin_amdgcn_exp2f(sc[qs][jb][r] + srv[jb]);
                    psum += p;
                    union { float f; unsigned u; } v; v.f = p;
                    PS[w * 2 + qs][prow][16 * jb + ln] = (ushort)((v.u + 0x8000u) >> 16);
                }
                lsum[qs][r] += psum;
            }

        // PV: B[k=t][n=d] from frT[d][t] global (shared by both q-sets)
        bf16x8 fb0[4], fb1[4];
        #pragma unroll
        for (int jb = 0; jb < 4; ++jb) {
            const ushort* p = ftb + (size_t)(16 * jb + ln) * S_ + t0 + quad * 8;
            fb0[jb] = *(const bf16x8*)p;
            fb1[jb] = *(const bf16x8*)(p + 32);
        }
        #pragma unroll
        for (int qs = 0; qs < 2; ++qs) {
            const bf16x8 pa0 = *(const bf16x8*)&PS[w * 2 + qs][ln][quad * 8];
            const bf16x8 pa1 = *(const bf16x8*)&PS[w * 2 + qs][ln][32 + quad * 8];
            #pragma unroll
            for (int jb = 0; jb < 4; ++jb) {
                ctx[qs][jb] = __builtin_amdgcn_mfma_f32_16x16x32_bf16(pa0, fb0[jb], ctx[qs][jb], 0, 0, 0);
                ctx[qs][jb] = __builtin_amdgcn_mfma_f32_16x16x32_bf16(pa1, fb1[jb], ctx[qs][jb], 0, 0, 0);
            }
        }
    }

    #pragma unroll
    for (int qs = 0; qs < 2; ++qs)
        #pragma unroll
        for (int r = 0; r < 4; ++r) {
            float l = lsum[qs][r];
            #pragma unroll
            for (int off = 8; off; off >>= 1) l += __shfl_xor(l, off, 16);
            const float inv = 1.f / l;
            const int q = q0 + w * 32 + qs * 16 + quad * 4 + r;
            ushort* orow = hsa + (size_t)(b * S_ + q) * D_ + h * 64;
            #pragma unroll
            for (int jb = 0; jb < 4; ++jb)
                orow[16 * jb + ln] = f2bf(ctx[qs][jb][r] * inv);
        }
}

// ---------------------------------------------------------------------------
// LayerNorm(h + fh) * g + b
// ---------------------------------------------------------------------------
__global__ __launch_bounds__(256) void ln_kernel(
    const float* __restrict__ h, const float* __restrict__ fh,
    const float* __restrict__ g, const float* __restrict__ bb,
    float* __restrict__ out)
{
    const int row = blockIdx.x, tid = threadIdx.x;
    const float* hp = h + (size_t)row * 512;
    const float* fp = fh + (size_t)row * 512;
    const float x0 = hp[tid] + fp[tid];
    const float x1 = hp[tid + 256] + fp[tid + 256];
    __shared__ float red[4];

    float s = x0 + x1;
    #pragma unroll
    for (int off = 32; off; off >>= 1) s += __shfl_xor(s, off, 64);
    if ((tid & 63) == 0) red[tid >> 6] = s;
    __syncthreads();
    const float mu = (red[0] + red[1] + red[2] + red[3]) * (1.f / 512.f);

    const float d0 = x0 - mu, d1 = x1 - mu;
    float v = d0 * d0 + d1 * d1;
    #pragma unroll
    for (int off = 32; off; off >>= 1) v += __shfl_xor(v, off, 64);
    __syncthreads();
    if ((tid & 63) == 0) red[tid >> 6] = v;
    __syncthreads();
    const float var = (red[0] + red[1] + red[2] + red[3]) * (1.f / 512.f);
    const float inv = rsqrtf(var + LN_EPS);

    out[(size_t)row * 512 + tid] = d0 * inv * g[tid] + bb[tid];
    out[(size_t)row * 512 + tid + 256] = d1 * inv * g[tid + 256] + bb[tid + 256];
}

// ---------------------------------------------------------------------------
extern "C" void kernel_launch(void* const* d_in, const int* in_sizes, int n_in,
                              void* d_out, int out_size, void* d_ws, size_t ws_size,
                              hipStream_t stream)
{
    const float* h   = (const float*)d_in[0];
    const float* rh  = (const float*)d_in[1];
    // d_in[2] = Wl, d_in[4] = al : unused — sl cancels in softmax
    const float* Wr  = (const float*)d_in[3];
    const float* ar  = (const float*)d_in[5];
    const float* Wrs = (const float*)d_in[6];
    const float* Wrt = (const float*)d_in[7];
    const float* Wf  = (const float*)d_in[8];
    const float* lng = (const float*)d_in[9];
    const float* lnb = (const float*)d_in[10];
    float* out = (float*)d_out;
    char* wsb  = (char*)d_ws;

    const size_t MB = (size_t)1 << 20;
    ushort* hb   = (ushort*)(wsb);               //  8 MB  h bf16 [8192,512]
    ushort* rhb  = (ushort*)(wsb + 8 * MB);      //  1 MB  rh bf16 [8192,64]
    ushort* WrT  = (ushort*)(wsb + 9 * MB);      // .5 MB  [512,512]
    ushort* WfT  = (ushort*)(wsb + 9 * MB + 512 * 1024);
    ushort* WrsT = (ushort*)(wsb + 10 * MB);     // 64 KB  [512,64]
    ushort* WrtT = (ushort*)(wsb + 10 * MB + 64 * 1024);
    ushort* frT  = (ushort*)(wsb + 11 * MB);     //  8 MB  [B,H,64,S]
    ushort* rkw  = (ushort*)(wsb + 19 * MB);     //  8 MB  [B,H,S,64]
    ushort* rqw  = (ushort*)(wsb + 27 * MB);     //  8 MB  [B,H,S,64]
    float*  sr   = (float*) (wsb + 35 * MB);     // .25MB  [B,H,S]
    ushort* hsab = (ushort*)(wsb + 36 * MB);     //  8 MB  [B,S,512] bf16
    float*  fh   = (float*) (wsb + 44 * MB);     // 16 MB  [B,S,512] f32
    // total 60 MB

    dim3 blk(256);
    cast4<<<4096, blk, 0, stream>>>(h, hb);
    cast4<<<512, blk, 0, stream>>>(rh, rhb);
    tcast<<<1024, blk, 0, stream>>>(Wr, WrT, 512, 9);
    tcast<<<1024, blk, 0, stream>>>(Wf, WfT, 512, 9);
    tcast<<<128, blk, 0, stream>>>(Wrs, WrsT, 64, 6);
    tcast<<<128, blk, 0, stream>>>(Wrt, WrtT, 64, 6);

    dim3 gG(128, 4);
    // fr projection -> frT bf16 + sr (leaky·ar, ×LOG2E)
    mfma_gemm<2><<<gG, blk, 0, stream>>>(hb, WrT, frT, sr, ar, 512, LOG2E,
                                         nullptr, nullptr, 0.f);
    // relation projections fused (z=2): rk ×LOG2E, rq ×1
    mfma_gemm<3><<<dim3(128, 4, 2), blk, 0, stream>>>(
        rhb, WrsT, rkw, nullptr, nullptr, 64, LOG2E, WrtT, rqw, 1.0f);
    // attention -> hsa bf16
    attn_mfma<<<dim3(S_ / 128, H_, B_), blk, 0, stream>>>(frT, rkw, rqw, sr, hsab);
    // final projection -> fh f32
    mfma_gemm<0><<<gG, blk, 0, stream>>>(hsab, WfT, fh, nullptr, nullptr, 512, 1.0f,
                                         nullptr, nullptr, 0.f);
    // residual + layernorm
    ln_kernel<<<dim3(B_ * S_), blk, 0, stream>>>(h, fh, lng, lnb, out);
}

// Round 6
// 191.055 us; speedup vs baseline: 1.3705x; 1.3705x over previous
//
#include <hip/hip_runtime.h>
#include <math.h>

#define B_ 4
#define S_ 2048
#define D_ 512
#define H_ 8
#define HD_ 64
#define RL_ 64
#define LN_EPS 1e-5f
#define SLOPE 0.01f
#define LOG2E 1.4426950408889634f

typedef __attribute__((ext_vector_type(8))) __bf16 bf16x8;
typedef __attribute__((ext_vector_type(4))) float f32x4;

__device__ __forceinline__ float leaky(float x) { return x >= 0.f ? x : SLOPE * x; }

// float -> bf16 (RNE)
__device__ __forceinline__ ushort f2bf(float f) {
    union { float f; unsigned u; } v; v.f = f;
    unsigned r = v.u + 0x7fffu + ((v.u >> 16) & 1u);
    return (ushort)(r >> 16);
}

__device__ __forceinline__ void g2lds16(const void* g, void* l) {
    __builtin_amdgcn_global_load_lds(
        (const __attribute__((address_space(1))) void*)(uintptr_t)g,
        (__attribute__((address_space(3))) void*)(uintptr_t)l, 16, 0, 0);
}

// ---------------------------------------------------------------------------
// prep: all input casts fused into one launch (grid = 6912 blocks)
//   [0,4096)    h  f32[8192,512] -> hb bf16
//   [4096,4608) rh f32[8192,64]  -> rhb bf16
//   [4608,5632) Wr [512][512]    -> WrT [512][512] (transposed bf16)
//   [5632,6656) Wf                -> WfT
//   [6656,6784) Wrs [64][512]    -> WrsT [512][64]
//   [6784,6912) Wrt              -> WrtT
// ---------------------------------------------------------------------------
__global__ __launch_bounds__(256) void prep(
    const float* __restrict__ h, const float* __restrict__ rh,
    const float* __restrict__ Wr, const float* __restrict__ Wf,
    const float* __restrict__ Wrs, const float* __restrict__ Wrt,
    ushort* __restrict__ hb, ushort* __restrict__ rhb,
    ushort* __restrict__ WrT, ushort* __restrict__ WfT,
    ushort* __restrict__ WrsT, ushort* __restrict__ WrtT)
{
    const int bx = blockIdx.x, tid = threadIdx.x;
    if (bx < 4608) {
        const float* in = (bx < 4096) ? h : rh;
        ushort* o = (bx < 4096) ? hb : rhb;
        const int i = (bx < 4096 ? bx : bx - 4096) * 256 + tid;
        const float4 v = ((const float4*)in)[i];
        ushort4 u; u.x = f2bf(v.x); u.y = f2bf(v.y); u.z = f2bf(v.z); u.w = f2bf(v.w);
        ((ushort4*)o)[i] = u;
    } else if (bx < 6656) {
        const float* in = (bx < 5632) ? Wr : Wf;
        ushort* o = (bx < 5632) ? WrT : WfT;
        const int idx = (bx - (bx < 5632 ? 4608 : 5632)) * 256 + tid;
        const int k = idx & 511, n = idx >> 9;
        o[idx] = f2bf(in[k * 512 + n]);
    } else {
        const float* in = (bx < 6784) ? Wrs : Wrt;
        ushort* o = (bx < 6784) ? WrsT : WrtT;
        const int idx = (bx - (bx < 6784 ? 6656 : 6784)) * 256 + tid;
        const int k = idx & 63, n = idx >> 6;
        o[idx] = f2bf(in[k * 512 + n]);
    }
}

// ---------------------------------------------------------------------------
// MFMA GEMM: C[M,512] = A[M,K]bf16 @ W (WT[512,K] bf16, n-major).
// 64x128 tile -> 512 blocks. 4 waves in 2x2 (wave = 32m x 64n). (R5-proven.)
// MODE 0: fp32 store C[M,512]
// MODE 2: frT[b,h,d,s] bf16 store + sred = scale * sum_d leaky(c)*avec[d]
// MODE 3: bf16 store [b,h,s,64] scaled; gridDim.z=2 fuses both relation projs
// ---------------------------------------------------------------------------
template <int MODE>
__global__ __launch_bounds__(256) void mfma_gemm(
    const ushort* __restrict__ A, const ushort* __restrict__ WT,
    void* __restrict__ Cout, float* __restrict__ sred,
    const float* __restrict__ avec, int K, float scale,
    const ushort* __restrict__ WT2, void* __restrict__ Cout2, float scale2)
{
    __shared__ ushort As[64 * 32];
    __shared__ ushort Bs[128 * 32];

    const int tid = threadIdx.x;
    const int lane = tid & 63, w = tid >> 6;
    const int ln = lane & 15, quad = lane >> 4;
    const int wm = w >> 1, wn = w & 1;
    const int m0 = blockIdx.x * 64, n0 = blockIdx.y * 128;

    const ushort* wt = WT; void* co = Cout; float scl = scale;
    if constexpr (MODE == 3) {
        if (blockIdx.z) { wt = WT2; co = Cout2; scl = scale2; }
    }

    const int srA = tid >> 2;
    const int lchA = ((lane & 3) - (srA >> 1)) & 3;
    const ushort* Ag = A + (size_t)(m0 + srA) * K + lchA * 8;
    ushort* AsL = As + (size_t)tid * 8;
    const int srB = w * 32 + (lane >> 2);
    const int lchB = ((lane & 3) - (srB >> 1)) & 3;
    const ushort* Bg0 = wt + (size_t)(n0 + srB) * K + lchB * 8;
    const ushort* Bg1 = Bg0 + (size_t)16 * K;
    ushort* BsL = Bs + srB * 32 + (lane & 3) * 8;

    const int pc = (quad + (ln >> 1)) & 3;

    f32x4 acc[2][4] = {};
    for (int k0 = 0; k0 < K; k0 += 32) {
        __syncthreads();
        g2lds16(Ag, AsL);
        g2lds16(Bg0, BsL); g2lds16(Bg1, BsL + 512);
        Ag += 32; Bg0 += 32; Bg1 += 32;
        __syncthreads();

        bf16x8 af[2], bfr[4];
        #pragma unroll
        for (int mi = 0; mi < 2; ++mi)
            af[mi] = *(const bf16x8*)&As[(wm * 32 + mi * 16 + ln) * 32 + pc * 8];
        #pragma unroll
        for (int ni = 0; ni < 4; ++ni)
            bfr[ni] = *(const bf16x8*)&Bs[(wn * 64 + ni * 16 + ln) * 32 + pc * 8];
        #pragma unroll
        for (int mi = 0; mi < 2; ++mi)
            #pragma unroll
            for (int ni = 0; ni < 4; ++ni)
                acc[mi][ni] = __builtin_amdgcn_mfma_f32_16x16x32_bf16(
                    af[mi], bfr[ni], acc[mi][ni], 0, 0, 0);
    }

    if constexpr (MODE == 0) {
        float* C = (float*)co;
        #pragma unroll
        for (int mi = 0; mi < 2; ++mi) {
            const int row = m0 + wm * 32 + mi * 16 + quad * 4;
            #pragma unroll
            for (int ni = 0; ni < 4; ++ni) {
                const int col = n0 + wn * 64 + ni * 16 + ln;
                #pragma unroll
                for (int r = 0; r < 4; ++r)
                    C[(size_t)(row + r) * 512 + col] = acc[mi][ni][r];
            }
        }
    }
    if constexpr (MODE == 2 || MODE == 3) {
        const int head = blockIdx.y * 2 + wn;
        const int b = m0 >> 11;
        const size_t bh = (size_t)b * H_ + head;
        if constexpr (MODE == 2) {
            ushort* frT = (ushort*)co;
            #pragma unroll
            for (int mi = 0; mi < 2; ++mi) {
                const int s = (m0 & (S_ - 1)) + wm * 32 + mi * 16 + quad * 4;
                #pragma unroll
                for (int ni = 0; ni < 4; ++ni) {
                    const int d = ni * 16 + ln;
                    ushort4 o;
                    o.x = f2bf(acc[mi][ni][0]); o.y = f2bf(acc[mi][ni][1]);
                    o.z = f2bf(acc[mi][ni][2]); o.w = f2bf(acc[mi][ni][3]);
                    *(ushort4*)(frT + (bh * 64 + d) * S_ + s) = o;
                }
            }
            float a4[4];
            #pragma unroll
            for (int ni = 0; ni < 4; ++ni) a4[ni] = avec[ni * 16 + ln];
            #pragma unroll
            for (int mi = 0; mi < 2; ++mi) {
                const int s = (m0 & (S_ - 1)) + wm * 32 + mi * 16 + quad * 4;
                #pragma unroll
                for (int r = 0; r < 4; ++r) {
                    float v = 0.f;
                    #pragma unroll
                    for (int ni = 0; ni < 4; ++ni)
                        v += leaky(acc[mi][ni][r]) * a4[ni];
                    #pragma unroll
                    for (int off = 8; off; off >>= 1) v += __shfl_xor(v, off, 16);
                    if (ln == 0) sred[bh * S_ + s + r] = v * scl;
                }
            }
        }
        if constexpr (MODE == 3) {
            ushort* O = (ushort*)co;
            #pragma unroll
            for (int mi = 0; mi < 2; ++mi) {
                const int s = (m0 & (S_ - 1)) + wm * 32 + mi * 16 + quad * 4;
                #pragma unroll
                for (int ni = 0; ni < 4; ++ni) {
                    const int d = ni * 16 + ln;
                    #pragma unroll
                    for (int r = 0; r < 4; ++r)
                        O[(bh * S_ + s + r) * 64 + d] = f2bf(acc[mi][ni][r] * scl);
                }
            }
        }
    }
}

// ---------------------------------------------------------------------------
// Flash attention, bf16 MFMA. 128 q / block (4 waves x 32 q), 64-t tiles.
// Double-buffered async staging: global_load_lds into XOR-swizzled unpadded
// tiles (granule phys = (logical + row) & 7 -> all LDS ops <=2-way per
// 16-lane phase = free). Prefetch t+1 -> compute t -> ONE barrier -> swap.
// No max-subtraction (scores pre-scaled by LOG2E); sl cancels in softmax.
// ---------------------------------------------------------------------------
__global__ __launch_bounds__(256) void attn_mfma(
    const ushort* __restrict__ frT, const ushort* __restrict__ rk,
    const ushort* __restrict__ rq, const float* __restrict__ sr,
    ushort* __restrict__ hsa)
{
    __shared__ ushort RQ[2][64][64];   // [t][r-granules], swizzled, 16 KB
    __shared__ ushort FT[2][64][64];   // [d][t-granules], swizzled, 16 KB
    __shared__ ushort PS[8][16][72];   // per-(wave,qs) P strips, 18 KB
    __shared__ float SRs[S_];          // 8 KB

    const int tid = threadIdx.x;
    const int w = tid >> 6;
    const int lane = tid & 63;
    const int ln = lane & 15;
    const int quad = lane >> 4;
    const int b = blockIdx.z, h = blockIdx.y, q0 = blockIdx.x * 128;
    const size_t bh = (size_t)b * H_ + h;

    for (int i = tid; i < S_; i += 256) SRs[i] = sr[bh * S_ + i];

    // A-frags (rk), 2 q-sets of 16
    const ushort* rkb = rk + ((bh * S_ + q0 + w * 32) << 6);
    bf16x8 a[2][2];
    #pragma unroll
    for (int qs = 0; qs < 2; ++qs) {
        const ushort* p = rkb + (qs * 16 + ln) * 64 + quad * 8;
        a[qs][0] = *(const bf16x8*)p;
        a[qs][1] = *(const bf16x8*)(p + 32);
    }

    const ushort* rqb = rq + (bh * S_ << 6);
    const ushort* ftb = frT + (size_t)bh * 64 * S_;

    // staging geometry: wave w covers tile rows [16w,16w+32) via 2 issues of
    // 8 rows; lane -> row offset rl = lane>>3, phys granule lane&7,
    // logical granule s = ((lane&7) - rl) & 7  (row swizzle, +8/+16 rows ≡ mod 8)
    const int rl = lane >> 3;
    const int sg = ((lane & 7) - rl) & 7;
    const int row0 = w * 16 + rl;          // + i*8 per issue

    #define STAGE(buf, t0)                                                        \
        {                                                                         \
            _Pragma("unroll")                                                     \
            for (int i = 0; i < 2; ++i) {                                         \
                const int tr = row0 + i * 8;                                      \
                g2lds16(rqb + ((size_t)((t0) + tr) << 6) + sg * 8,                \
                        &RQ[buf][tr][(lane & 7) * 8]);                            \
                g2lds16(ftb + (size_t)tr * S_ + (t0) + sg * 8,                    \
                        &FT[buf][tr][(lane & 7) * 8]);                            \
            }                                                                     \
        }

    STAGE(0, 0)
    __syncthreads();

    float lsum[2][4] = {};
    f32x4 ctx[2][4] = {};
    int buf = 0;

    for (int t0 = 0; t0 < S_; t0 += 64) {
        if (t0 + 64 < S_) STAGE(buf ^ 1, t0 + 64)

        // ---- QK^T: B[k=r][n=t] from RQ[t][r] (swizzled granules) ----
        f32x4 sc[2][4];
        #pragma unroll
        for (int jb = 0; jb < 4; ++jb) {
            const int tr = 16 * jb + ln;
            const bf16x8 b0 = *(const bf16x8*)&RQ[buf][tr][((quad + tr) & 7) * 8];
            const bf16x8 b1 = *(const bf16x8*)&RQ[buf][tr][((quad + 4 + tr) & 7) * 8];
            #pragma unroll
            for (int qs = 0; qs < 2; ++qs) {
                f32x4 t = {0.f, 0.f, 0.f, 0.f};
                t = __builtin_amdgcn_mfma_f32_16x16x32_bf16(a[qs][0], b0, t, 0, 0, 0);
                t = __builtin_amdgcn_mfma_f32_16x16x32_bf16(a[qs][1], b1, t, 0, 0, 0);
                sc[qs][jb] = t;
            }
        }

        float srv[4];
        #pragma unroll
        for (int jb = 0; jb < 4; ++jb) srv[jb] = SRs[t0 + 16 * jb + ln];

        // ---- softmax (exp2, no max, trunc pack) -> P strips ----
        #pragma unroll
        for (int qs = 0; qs < 2; ++qs)
            #pragma unroll
            for (int r = 0; r < 4; ++r) {
                const int prow = quad * 4 + r;
                float psum = 0.f;
                #pragma unroll
                for (int jb = 0; jb < 4; ++jb) {
                    const float p = __builtin_amdgcn_exp2f(sc[qs][jb][r] + srv[jb]);
                    psum += p;
                    union { float f; unsigned u; } v; v.f = p;
                    PS[w * 2 + qs][prow][16 * jb + ln] = (ushort)(v.u >> 16);
                }
                lsum[qs][r] += psum;
            }

        // ---- PV: B[k=t][n=d] from FT[d][t] (swizzled granules) ----
        bf16x8 fb0[4], fb1[4];
        #pragma unroll
        for (int jb = 0; jb < 4; ++jb) {
            const int dr = 16 * jb + ln;
            fb0[jb] = *(const bf16x8*)&FT[buf][dr][((quad + dr) & 7) * 8];
            fb1[jb] = *(const bf16x8*)&FT[buf][dr][((quad + 4 + dr) & 7) * 8];
        }
        #pragma unroll
        for (int qs = 0; qs < 2; ++qs) {
            const bf16x8 pa0 = *(const bf16x8*)&PS[w * 2 + qs][ln][quad * 8];
            const bf16x8 pa1 = *(const bf16x8*)&PS[w * 2 + qs][ln][32 + quad * 8];
            #pragma unroll
            for (int jb = 0; jb < 4; ++jb) {
                ctx[qs][jb] = __builtin_amdgcn_mfma_f32_16x16x32_bf16(pa0, fb0[jb], ctx[qs][jb], 0, 0, 0);
                ctx[qs][jb] = __builtin_amdgcn_mfma_f32_16x16x32_bf16(pa1, fb1[jb], ctx[qs][jb], 0, 0, 0);
            }
        }

        __syncthreads();   // drains prefetch (vmcnt) + guards buffer reuse
        buf ^= 1;
    }

    #pragma unroll
    for (int qs = 0; qs < 2; ++qs)
        #pragma unroll
        for (int r = 0; r < 4; ++r) {
            float l = lsum[qs][r];
            #pragma unroll
            for (int off = 8; off; off >>= 1) l += __shfl_xor(l, off, 16);
            const float inv = 1.f / l;
            const int q = q0 + w * 32 + qs * 16 + quad * 4 + r;
            ushort* orow = hsa + (size_t)(b * S_ + q) * D_ + h * 64;
            #pragma unroll
            for (int jb = 0; jb < 4; ++jb)
                orow[16 * jb + ln] = f2bf(ctx[qs][jb][r] * inv);
        }
}

// ---------------------------------------------------------------------------
// LayerNorm(h + fh) * g + b
// ---------------------------------------------------------------------------
__global__ __launch_bounds__(256) void ln_kernel(
    const float* __restrict__ h, const float* __restrict__ fh,
    const float* __restrict__ g, const float* __restrict__ bb,
    float* __restrict__ out)
{
    const int row = blockIdx.x, tid = threadIdx.x;
    const float* hp = h + (size_t)row * 512;
    const float* fp = fh + (size_t)row * 512;
    const float x0 = hp[tid] + fp[tid];
    const float x1 = hp[tid + 256] + fp[tid + 256];
    __shared__ float red[4];

    float s = x0 + x1;
    #pragma unroll
    for (int off = 32; off; off >>= 1) s += __shfl_xor(s, off, 64);
    if ((tid & 63) == 0) red[tid >> 6] = s;
    __syncthreads();
    const float mu = (red[0] + red[1] + red[2] + red[3]) * (1.f / 512.f);

    const float d0 = x0 - mu, d1 = x1 - mu;
    float v = d0 * d0 + d1 * d1;
    #pragma unroll
    for (int off = 32; off; off >>= 1) v += __shfl_xor(v, off, 64);
    __syncthreads();
    if ((tid & 63) == 0) red[tid >> 6] = v;
    __syncthreads();
    const float var = (red[0] + red[1] + red[2] + red[3]) * (1.f / 512.f);
    const float inv = rsqrtf(var + LN_EPS);

    out[(size_t)row * 512 + tid] = d0 * inv * g[tid] + bb[tid];
    out[(size_t)row * 512 + tid + 256] = d1 * inv * g[tid + 256] + bb[tid + 256];
}

// ---------------------------------------------------------------------------
extern "C" void kernel_launch(void* const* d_in, const int* in_sizes, int n_in,
                              void* d_out, int out_size, void* d_ws, size_t ws_size,
                              hipStream_t stream)
{
    const float* h   = (const float*)d_in[0];
    const float* rh  = (const float*)d_in[1];
    // d_in[2] = Wl, d_in[4] = al : unused — sl cancels in softmax
    const float* Wr  = (const float*)d_in[3];
    const float* ar  = (const float*)d_in[5];
    const float* Wrs = (const float*)d_in[6];
    const float* Wrt = (const float*)d_in[7];
    const float* Wf  = (const float*)d_in[8];
    const float* lng = (const float*)d_in[9];
    const float* lnb = (const float*)d_in[10];
    float* out = (float*)d_out;
    char* wsb  = (char*)d_ws;

    const size_t MB = (size_t)1 << 20;
    ushort* hb   = (ushort*)(wsb);               //  8 MB  h bf16 [8192,512]
    ushort* rhb  = (ushort*)(wsb + 8 * MB);      //  1 MB  rh bf16 [8192,64]
    ushort* WrT  = (ushort*)(wsb + 9 * MB);      // .5 MB  [512,512]
    ushort* WfT  = (ushort*)(wsb + 9 * MB + 512 * 1024);
    ushort* WrsT = (ushort*)(wsb + 10 * MB);     // 64 KB  [512,64]
    ushort* WrtT = (ushort*)(wsb + 10 * MB + 64 * 1024);
    ushort* frT  = (ushort*)(wsb + 11 * MB);     //  8 MB  [B,H,64,S]
    ushort* rkw  = (ushort*)(wsb + 19 * MB);     //  8 MB  [B,H,S,64]
    ushort* rqw  = (ushort*)(wsb + 27 * MB);     //  8 MB  [B,H,S,64]
    float*  sr   = (float*) (wsb + 35 * MB);     // .25MB  [B,H,S]
    ushort* hsab = (ushort*)(wsb + 36 * MB);     //  8 MB  [B,S,512] bf16
    float*  fh   = (float*) (wsb + 44 * MB);     // 16 MB  [B,S,512] f32
    // total 60 MB

    dim3 blk(256);
    prep<<<dim3(6912), blk, 0, stream>>>(h, rh, Wr, Wf, Wrs, Wrt,
                                         hb, rhb, WrT, WfT, WrsT, WrtT);

    dim3 gG(128, 4);
    // fr projection -> frT bf16 + sr (leaky·ar, ×LOG2E)
    mfma_gemm<2><<<gG, blk, 0, stream>>>(hb, WrT, frT, sr, ar, 512, LOG2E,
                                         nullptr, nullptr, 0.f);
    // relation projections fused (z=2): rk ×LOG2E, rq ×1
    mfma_gemm<3><<<dim3(128, 4, 2), blk, 0, stream>>>(
        rhb, WrsT, rkw, nullptr, nullptr, 64, LOG2E, WrtT, rqw, 1.0f);
    // attention -> hsa bf16
    attn_mfma<<<dim3(S_ / 128, H_, B_), blk, 0, stream>>>(frT, rkw, rqw, sr, hsab);
    // final projection -> fh f32
    mfma_gemm<0><<<gG, blk, 0, stream>>>(hsab, WfT, fh, nullptr, nullptr, 512, 1.0f,
                                         nullptr, nullptr, 0.f);
    // residual + layernorm
    ln_kernel<<<dim3(B_ * S_), blk, 0, stream>>>(h, fh, lng, lnb, out);
}

// Round 7
// 184.574 us; speedup vs baseline: 1.4187x; 1.0351x over previous
//
#include <hip/hip_runtime.h>
#include <math.h>

#define B_ 4
#define S_ 2048
#define D_ 512
#define H_ 8
#define HD_ 64
#define RL_ 64
#define LN_EPS 1e-5f
#define SLOPE 0.01f
#define LOG2E 1.4426950408889634f

typedef __attribute__((ext_vector_type(8))) __bf16 bf16x8;
typedef __attribute__((ext_vector_type(4))) float f32x4;

__device__ __forceinline__ float leaky(float x) { return x >= 0.f ? x : SLOPE * x; }

// float -> bf16 (RNE)
__device__ __forceinline__ ushort f2bf(float f) {
    union { float f; unsigned u; } v; v.f = f;
    unsigned r = v.u + 0x7fffu + ((v.u >> 16) & 1u);
    return (ushort)(r >> 16);
}
__device__ __forceinline__ unsigned fbits(float f) {
    union { float f; unsigned u; } v; v.f = f; return v.u;
}

__device__ __forceinline__ void g2lds16(const void* g, void* l) {
    __builtin_amdgcn_global_load_lds(
        (const __attribute__((address_space(1))) void*)(uintptr_t)g,
        (__attribute__((address_space(3))) void*)(uintptr_t)l, 16, 0, 0);
}

// ---------------------------------------------------------------------------
// prep_cast: h, rh f32 -> bf16 (vectorized). grid 4608.
// ---------------------------------------------------------------------------
__global__ __launch_bounds__(256) void prep_cast(
    const float* __restrict__ h, const float* __restrict__ rh,
    ushort* __restrict__ hb, ushort* __restrict__ rhb)
{
    const int bx = blockIdx.x, tid = threadIdx.x;
    const float* in = (bx < 4096) ? h : rh;
    ushort* o = (bx < 4096) ? hb : rhb;
    const int i = (bx < 4096 ? bx : bx - 4096) * 256 + tid;
    const float4 v = ((const float4*)in)[i];
    ushort4 u; u.x = f2bf(v.x); u.y = f2bf(v.y); u.z = f2bf(v.z); u.w = f2bf(v.w);
    ((ushort4*)o)[i] = u;
}

// ---------------------------------------------------------------------------
// prep_tr: LDS-tiled transpose f32 [K][512] -> bf16 [512][K] (coalesced both
// sides). grid 144: Wr 64 tiles, Wf 64, Wrs 8, Wrt 8 (64x64 tiles).
// ---------------------------------------------------------------------------
__global__ __launch_bounds__(256) void prep_tr(
    const float* __restrict__ Wr, const float* __restrict__ Wf,
    const float* __restrict__ Wrs, const float* __restrict__ Wrt,
    ushort* __restrict__ WrT, ushort* __restrict__ WfT,
    ushort* __restrict__ WrsT, ushort* __restrict__ WrtT)
{
    __shared__ float TS[64][65];
    int bx = blockIdx.x;
    const float* in; ushort* out; int K, tk, tn;
    if (bx < 64)       { in = Wr;  out = WrT;  K = 512; tk = bx & 7; tn = bx >> 3; }
    else if (bx < 128) { in = Wf;  out = WfT;  K = 512; bx -= 64; tk = bx & 7; tn = bx >> 3; }
    else if (bx < 136) { in = Wrs; out = WrsT; K = 64;  tk = 0; tn = bx - 128; }
    else               { in = Wrt; out = WrtT; K = 64;  tk = 0; tn = bx - 136; }
    const int k0 = tk * 64, n0 = tn * 64;
    const int r = threadIdx.x >> 4, c4 = (threadIdx.x & 15) * 4;
    #pragma unroll
    for (int p = 0; p < 4; ++p) {
        const int row = r + 16 * p;
        const float4 v = *(const float4*)(in + (size_t)(k0 + row) * 512 + n0 + c4);
        TS[row][c4] = v.x; TS[row][c4 + 1] = v.y;
        TS[row][c4 + 2] = v.z; TS[row][c4 + 3] = v.w;
    }
    __syncthreads();
    #pragma unroll
    for (int p = 0; p < 4; ++p) {
        const int nn = r + 16 * p;
        ushort4 o;
        o.x = f2bf(TS[c4 + 0][nn]); o.y = f2bf(TS[c4 + 1][nn]);
        o.z = f2bf(TS[c4 + 2][nn]); o.w = f2bf(TS[c4 + 3][nn]);
        *(ushort4*)(out + (size_t)(n0 + nn) * K + k0 + c4) = o;
    }
}

// ---------------------------------------------------------------------------
// MFMA GEMM, double-buffered: C[M,512] = A[M,K]bf16 @ WT[512,K]bf16.
// 64x128 tile, BK=32, 4 waves 2x2. Stage k+1 into buf^1 BEFORE computing k
// -> one barrier per k-step, load latency hidden behind MFMA.
// MODE 0: fp32 C[M,512]; MODE 2: frT + sred; MODE 3: bf16 [b,h,s,64], z fused.
// ---------------------------------------------------------------------------
template <int MODE>
__global__ __launch_bounds__(256) void mfma_gemm(
    const ushort* __restrict__ A, const ushort* __restrict__ WT,
    void* __restrict__ Cout, float* __restrict__ sred,
    const float* __restrict__ avec, int K, float scale,
    const ushort* __restrict__ WT2, void* __restrict__ Cout2, float scale2)
{
    __shared__ ushort As[2][64 * 32];
    __shared__ ushort Bs[2][128 * 32];

    const int tid = threadIdx.x;
    const int lane = tid & 63, w = tid >> 6;
    const int ln = lane & 15, quad = lane >> 4;
    const int wm = w >> 1, wn = w & 1;
    const int m0 = blockIdx.x * 64, n0 = blockIdx.y * 128;

    const ushort* wt = WT; void* co = Cout; float scl = scale;
    if constexpr (MODE == 3) {
        if (blockIdx.z) { wt = WT2; co = Cout2; scl = scale2; }
    }

    const int srA = tid >> 2;
    const int lchA = ((lane & 3) - (srA >> 1)) & 3;
    const ushort* AgB = A + (size_t)(m0 + srA) * K + lchA * 8;
    const int srB = w * 32 + (lane >> 2);
    const int lchB = ((lane & 3) - (srB >> 1)) & 3;
    const ushort* BgB0 = wt + (size_t)(n0 + srB) * K + lchB * 8;
    const ushort* BgB1 = BgB0 + (size_t)16 * K;
    const int aoff = tid * 8;
    const int boff = srB * 32 + (lane & 3) * 8;

    const int pc = (quad + (ln >> 1)) & 3;

    g2lds16(AgB, &As[0][aoff]);
    g2lds16(BgB0, &Bs[0][boff]);
    g2lds16(BgB1, &Bs[0][boff + 512]);

    f32x4 acc[2][4] = {};
    int buf = 0;
    for (int k0 = 0; k0 < K; k0 += 32) {
        __syncthreads();
        if (k0 + 32 < K) {
            g2lds16(AgB + k0 + 32, &As[buf ^ 1][aoff]);
            g2lds16(BgB0 + k0 + 32, &Bs[buf ^ 1][boff]);
            g2lds16(BgB1 + k0 + 32, &Bs[buf ^ 1][boff + 512]);
        }
        bf16x8 af[2], bfr[4];
        #pragma unroll
        for (int mi = 0; mi < 2; ++mi)
            af[mi] = *(const bf16x8*)&As[buf][(wm * 32 + mi * 16 + ln) * 32 + pc * 8];
        #pragma unroll
        for (int ni = 0; ni < 4; ++ni)
            bfr[ni] = *(const bf16x8*)&Bs[buf][(wn * 64 + ni * 16 + ln) * 32 + pc * 8];
        #pragma unroll
        for (int mi = 0; mi < 2; ++mi)
            #pragma unroll
            for (int ni = 0; ni < 4; ++ni)
                acc[mi][ni] = __builtin_amdgcn_mfma_f32_16x16x32_bf16(
                    af[mi], bfr[ni], acc[mi][ni], 0, 0, 0);
        buf ^= 1;
    }

    if constexpr (MODE == 0) {
        float* C = (float*)co;
        #pragma unroll
        for (int mi = 0; mi < 2; ++mi) {
            const int row = m0 + wm * 32 + mi * 16 + quad * 4;
            #pragma unroll
            for (int ni = 0; ni < 4; ++ni) {
                const int col = n0 + wn * 64 + ni * 16 + ln;
                #pragma unroll
                for (int r = 0; r < 4; ++r)
                    C[(size_t)(row + r) * 512 + col] = acc[mi][ni][r];
            }
        }
    }
    if constexpr (MODE == 2 || MODE == 3) {
        const int head = blockIdx.y * 2 + wn;
        const int b = m0 >> 11;
        const size_t bh = (size_t)b * H_ + head;
        if constexpr (MODE == 2) {
            ushort* frT = (ushort*)co;
            #pragma unroll
            for (int mi = 0; mi < 2; ++mi) {
                const int s = (m0 & (S_ - 1)) + wm * 32 + mi * 16 + quad * 4;
                #pragma unroll
                for (int ni = 0; ni < 4; ++ni) {
                    const int d = ni * 16 + ln;
                    ushort4 o;
                    o.x = f2bf(acc[mi][ni][0]); o.y = f2bf(acc[mi][ni][1]);
                    o.z = f2bf(acc[mi][ni][2]); o.w = f2bf(acc[mi][ni][3]);
                    *(ushort4*)(frT + (bh * 64 + d) * S_ + s) = o;
                }
            }
            float a4[4];
            #pragma unroll
            for (int ni = 0; ni < 4; ++ni) a4[ni] = avec[ni * 16 + ln];
            #pragma unroll
            for (int mi = 0; mi < 2; ++mi) {
                const int s = (m0 & (S_ - 1)) + wm * 32 + mi * 16 + quad * 4;
                #pragma unroll
                for (int r = 0; r < 4; ++r) {
                    float v = 0.f;
                    #pragma unroll
                    for (int ni = 0; ni < 4; ++ni)
                        v += leaky(acc[mi][ni][r]) * a4[ni];
                    #pragma unroll
                    for (int off = 8; off; off >>= 1) v += __shfl_xor(v, off, 16);
                    if (ln == 0) sred[bh * S_ + s + r] = v * scl;
                }
            }
        }
        if constexpr (MODE == 3) {
            ushort* O = (ushort*)co;
            #pragma unroll
            for (int mi = 0; mi < 2; ++mi) {
                const int s = (m0 & (S_ - 1)) + wm * 32 + mi * 16 + quad * 4;
                #pragma unroll
                for (int ni = 0; ni < 4; ++ni) {
                    const int d = ni * 16 + ln;
                    #pragma unroll
                    for (int r = 0; r < 4; ++r)
                        O[(bh * S_ + s + r) * 64 + d] = f2bf(acc[mi][ni][r] * scl);
                }
            }
        }
    }
}

// ---------------------------------------------------------------------------
// Flash attention, bf16 MFMA. 64 q / block (4 waves x 16 q), grid 1024
// -> 4 blocks/CU (LDS exactly 40 KB). Double-buffered async staging.
// t-INTERLEAVED score layout: score tile jb has n=ln <-> t = 4*ln + jb, so a
// lane's 4 P-values are adjacent in t -> ONE ds_write_b64 per r (was 4 b16),
// and sr reads become one float4 global load (L2-resident; SRs LDS deleted).
// Swizzles: RQ phys_granule = (g + (row>>2))&7 (rows read at stride 4);
// FT/PS phys = (g + row)&7. All LDS patterns <=2-way per phase = free.
// No max-subtraction (scores pre-scaled by LOG2E); sl cancels in softmax.
// ---------------------------------------------------------------------------
__global__ __launch_bounds__(256, 4) void attn_mfma(
    const ushort* __restrict__ frT, const ushort* __restrict__ rk,
    const ushort* __restrict__ rq, const float* __restrict__ sr,
    ushort* __restrict__ hsa)
{
    __shared__ ushort RQ[2][64][64];   // [t][r-granules swizzled] 16 KB
    __shared__ ushort FT[2][64][64];   // [d][t-granules swizzled] 16 KB
    __shared__ ushort PS[4][16][64];   // per-wave P strip [q][t], swizzled, 8 KB

    const int tid = threadIdx.x;
    const int w = tid >> 6;
    const int lane = tid & 63;
    const int ln = lane & 15;
    const int quad = lane >> 4;
    const int b = blockIdx.z, h = blockIdx.y, q0 = blockIdx.x * 64;
    const size_t bh = (size_t)b * H_ + h;

    // A-frags (rk): q = q0 + 16w + ln
    const ushort* rkb = rk + ((bh * S_ + q0 + w * 16 + ln) << 6);
    const bf16x8 a0 = *(const bf16x8*)(rkb + quad * 8);
    const bf16x8 a1 = *(const bf16x8*)(rkb + 32 + quad * 8);

    const ushort* rqb = rq + (bh * S_ << 6);
    const ushort* ftb = frT + (size_t)bh * 64 * S_;
    const float* srp = sr + bh * S_;

    // staging: wave w covers tile rows [16w, 16w+16), 2 issues of 8 rows
    const int rl = lane >> 3;              // 0..7
    const int pg = lane & 7;               // phys granule = lane&7
    const int row_b = w * 16 + rl;
    const int sgF = (pg - rl) & 7;                       // FT: (g+row)&7
    const int sgR0 = (pg - 4 * w - (rl >> 2)) & 7;       // RQ: (g+(row>>2))&7
    const int sgR1 = (pg - 4 * w - 2 - (rl >> 2)) & 7;

    #define STAGE(bf, t0)                                                     \
        {                                                                     \
            g2lds16(rqb + ((size_t)((t0) + row_b) << 6) + sgR0 * 8,           \
                    &RQ[bf][row_b][pg * 8]);                                  \
            g2lds16(rqb + ((size_t)((t0) + row_b + 8) << 6) + sgR1 * 8,       \
                    &RQ[bf][row_b + 8][pg * 8]);                              \
            g2lds16(ftb + (size_t)row_b * S_ + (t0) + sgF * 8,                \
                    &FT[bf][row_b][pg * 8]);                                  \
            g2lds16(ftb + (size_t)(row_b + 8) * S_ + (t0) + sgF * 8,          \
                    &FT[bf][row_b + 8][pg * 8]);                              \
        }

    STAGE(0, 0)
    __syncthreads();

    float lsum[4] = {};
    f32x4 ctx[4] = {};
    int buf = 0;

    for (int t0 = 0; t0 < S_; t0 += 64) {
        if (t0 + 64 < S_) STAGE(buf ^ 1, t0 + 64)
        const float4 srv = *(const float4*)(srp + t0 + 4 * ln);

        // ---- QK^T: tile jb -> t = 4*ln + jb; B rows tr = 4ln+jb ----
        f32x4 sc[4];
        #pragma unroll
        for (int jb = 0; jb < 4; ++jb) {
            const int tr = 4 * ln + jb;
            const bf16x8 b0 = *(const bf16x8*)&RQ[buf][tr][((quad + ln) & 7) * 8];
            const bf16x8 b1 = *(const bf16x8*)&RQ[buf][tr][((quad + 4 + ln) & 7) * 8];
            f32x4 t = {0.f, 0.f, 0.f, 0.f};
            t = __builtin_amdgcn_mfma_f32_16x16x32_bf16(a0, b0, t, 0, 0, 0);
            t = __builtin_amdgcn_mfma_f32_16x16x32_bf16(a1, b1, t, 0, 0, 0);
            sc[jb] = t;
        }

        // ---- softmax (exp2, no max) -> packed b64 P writes ----
        #pragma unroll
        for (int r = 0; r < 4; ++r) {
            const float p0 = __builtin_amdgcn_exp2f(sc[0][r] + srv.x);
            const float p1 = __builtin_amdgcn_exp2f(sc[1][r] + srv.y);
            const float p2 = __builtin_amdgcn_exp2f(sc[2][r] + srv.z);
            const float p3 = __builtin_amdgcn_exp2f(sc[3][r] + srv.w);
            lsum[r] += (p0 + p1) + (p2 + p3);
            const unsigned lo = (fbits(p0) >> 16) | (fbits(p1) & 0xffff0000u);
            const unsigned hi = (fbits(p2) >> 16) | (fbits(p3) & 0xffff0000u);
            const int prow = quad * 4 + r;
            *(uint2*)&PS[w][prow][(((ln >> 1) + prow) & 7) * 8 + (ln & 1) * 4] =
                make_uint2(lo, hi);
        }

        // ---- PV: A = P strip, B = FT[d][t] ----
        const bf16x8 pa0 = *(const bf16x8*)&PS[w][ln][((quad + ln) & 7) * 8];
        const bf16x8 pa1 = *(const bf16x8*)&PS[w][ln][((quad + 4 + ln) & 7) * 8];
        #pragma unroll
        for (int jb = 0; jb < 4; ++jb) {
            const bf16x8 fb0 = *(const bf16x8*)&FT[buf][16 * jb + ln][((quad + ln) & 7) * 8];
            const bf16x8 fb1 = *(const bf16x8*)&FT[buf][16 * jb + ln][((quad + 4 + ln) & 7) * 8];
            ctx[jb] = __builtin_amdgcn_mfma_f32_16x16x32_bf16(pa0, fb0, ctx[jb], 0, 0, 0);
            ctx[jb] = __builtin_amdgcn_mfma_f32_16x16x32_bf16(pa1, fb1, ctx[jb], 0, 0, 0);
        }

        __syncthreads();   // drains prefetch + guards buffer/PS reuse
        buf ^= 1;
    }

    #pragma unroll
    for (int r = 0; r < 4; ++r) {
        float l = lsum[r];
        #pragma unroll
        for (int off = 8; off; off >>= 1) l += __shfl_xor(l, off, 16);
        const float inv = 1.f / l;
        const int q = q0 + w * 16 + quad * 4 + r;
        ushort* orow = hsa + (size_t)(b * S_ + q) * D_ + h * 64;
        #pragma unroll
        for (int jb = 0; jb < 4; ++jb)
            orow[16 * jb + ln] = f2bf(ctx[jb][r] * inv);
    }
}

// ---------------------------------------------------------------------------
// LayerNorm(h + fh) * g + b
// ---------------------------------------------------------------------------
__global__ __launch_bounds__(256) void ln_kernel(
    const float* __restrict__ h, const float* __restrict__ fh,
    const float* __restrict__ g, const float* __restrict__ bb,
    float* __restrict__ out)
{
    const int row = blockIdx.x, tid = threadIdx.x;
    const float* hp = h + (size_t)row * 512;
    const float* fp = fh + (size_t)row * 512;
    const float x0 = hp[tid] + fp[tid];
    const float x1 = hp[tid + 256] + fp[tid + 256];
    __shared__ float red[4];

    float s = x0 + x1;
    #pragma unroll
    for (int off = 32; off; off >>= 1) s += __shfl_xor(s, off, 64);
    if ((tid & 63) == 0) red[tid >> 6] = s;
    __syncthreads();
    const float mu = (red[0] + red[1] + red[2] + red[3]) * (1.f / 512.f);

    const float d0 = x0 - mu, d1 = x1 - mu;
    float v = d0 * d0 + d1 * d1;
    #pragma unroll
    for (int off = 32; off; off >>= 1) v += __shfl_xor(v, off, 64);
    __syncthreads();
    if ((tid & 63) == 0) red[tid >> 6] = v;
    __syncthreads();
    const float var = (red[0] + red[1] + red[2] + red[3]) * (1.f / 512.f);
    const float inv = rsqrtf(var + LN_EPS);

    out[(size_t)row * 512 + tid] = d0 * inv * g[tid] + bb[tid];
    out[(size_t)row * 512 + tid + 256] = d1 * inv * g[tid + 256] + bb[tid + 256];
}

// ---------------------------------------------------------------------------
extern "C" void kernel_launch(void* const* d_in, const int* in_sizes, int n_in,
                              void* d_out, int out_size, void* d_ws, size_t ws_size,
                              hipStream_t stream)
{
    const float* h   = (const float*)d_in[0];
    const float* rh  = (const float*)d_in[1];
    // d_in[2] = Wl, d_in[4] = al : unused — sl cancels in softmax
    const float* Wr  = (const float*)d_in[3];
    const float* ar  = (const float*)d_in[5];
    const float* Wrs = (const float*)d_in[6];
    const float* Wrt = (const float*)d_in[7];
    const float* Wf  = (const float*)d_in[8];
    const float* lng = (const float*)d_in[9];
    const float* lnb = (const float*)d_in[10];
    float* out = (float*)d_out;
    char* wsb  = (char*)d_ws;

    const size_t MB = (size_t)1 << 20;
    ushort* hb   = (ushort*)(wsb);               //  8 MB  h bf16 [8192,512]
    ushort* rhb  = (ushort*)(wsb + 8 * MB);      //  1 MB  rh bf16 [8192,64]
    ushort* WrT  = (ushort*)(wsb + 9 * MB);      // .5 MB  [512,512]
    ushort* WfT  = (ushort*)(wsb + 9 * MB + 512 * 1024);
    ushort* WrsT = (ushort*)(wsb + 10 * MB);     // 64 KB  [512,64]
    ushort* WrtT = (ushort*)(wsb + 10 * MB + 64 * 1024);
    ushort* frT  = (ushort*)(wsb + 11 * MB);     //  8 MB  [B,H,64,S]
    ushort* rkw  = (ushort*)(wsb + 19 * MB);     //  8 MB  [B,H,S,64]
    ushort* rqw  = (ushort*)(wsb + 27 * MB);     //  8 MB  [B,H,S,64]
    float*  sr   = (float*) (wsb + 35 * MB);     // .25MB  [B,H,S]
    ushort* hsab = (ushort*)(wsb + 36 * MB);     //  8 MB  [B,S,512] bf16
    float*  fh   = (float*) (wsb + 44 * MB);     // 16 MB  [B,S,512] f32
    // total 60 MB

    dim3 blk(256);
    prep_cast<<<dim3(4608), blk, 0, stream>>>(h, rh, hb, rhb);
    prep_tr<<<dim3(144), blk, 0, stream>>>(Wr, Wf, Wrs, Wrt, WrT, WfT, WrsT, WrtT);

    dim3 gG(128, 4);
    // fr projection -> frT bf16 + sr (leaky·ar, ×LOG2E)
    mfma_gemm<2><<<gG, blk, 0, stream>>>(hb, WrT, frT, sr, ar, 512, LOG2E,
                                         nullptr, nullptr, 0.f);
    // relation projections fused (z=2): rk ×LOG2E, rq ×1
    mfma_gemm<3><<<dim3(128, 4, 2), blk, 0, stream>>>(
        rhb, WrsT, rkw, nullptr, nullptr, 64, LOG2E, WrtT, rqw, 1.0f);
    // attention -> hsa bf16 (64 q / block, 4 blocks/CU)
    attn_mfma<<<dim3(S_ / 64, H_, B_), blk, 0, stream>>>(frT, rkw, rqw, sr, hsab);
    // final projection -> fh f32
    mfma_gemm<0><<<gG, blk, 0, stream>>>(hsab, WfT, fh, nullptr, nullptr, 512, 1.0f,
                                         nullptr, nullptr, 0.f);
    // residual + layernorm
    ln_kernel<<<dim3(B_ * S_), blk, 0, stream>>>(h, fh, lng, lnb, out);
}

// Round 8
// 175.508 us; speedup vs baseline: 1.4919x; 1.0517x over previous
//
#include <hip/hip_runtime.h>
#include <math.h>

#define B_ 4
#define S_ 2048
#define D_ 512
#define H_ 8
#define HD_ 64
#define RL_ 64
#define LN_EPS 1e-5f
#define SLOPE 0.01f
#define LOG2E 1.4426950408889634f

typedef __attribute__((ext_vector_type(8))) __bf16 bf16x8;
typedef __attribute__((ext_vector_type(4))) float f32x4;

__device__ __forceinline__ float leaky(float x) { return x >= 0.f ? x : SLOPE * x; }

// float -> bf16 (RNE)
__device__ __forceinline__ ushort f2bf(float f) {
    union { float f; unsigned u; } v; v.f = f;
    unsigned r = v.u + 0x7fffu + ((v.u >> 16) & 1u);
    return (ushort)(r >> 16);
}
__device__ __forceinline__ unsigned fbits(float f) {
    union { float f; unsigned u; } v; v.f = f; return v.u;
}

__device__ __forceinline__ void g2lds16(const void* g, void* l) {
    __builtin_amdgcn_global_load_lds(
        (const __attribute__((address_space(1))) void*)(uintptr_t)g,
        (__attribute__((address_space(3))) void*)(uintptr_t)l, 16, 0, 0);
}

// ---------------------------------------------------------------------------
// prep (merged): grid 4752
//   [0,4096)    h f32 -> hb bf16       [4096,4608) rh -> rhb
//   [4608,4736) Wr/Wf 64x64-tile transpose -> WrT/WfT
//   [4736,4752) Wrs/Wrt transpose -> WrsT/WrtT
// ---------------------------------------------------------------------------
__global__ __launch_bounds__(256) void prep(
    const float* __restrict__ h, const float* __restrict__ rh,
    const float* __restrict__ Wr, const float* __restrict__ Wf,
    const float* __restrict__ Wrs, const float* __restrict__ Wrt,
    ushort* __restrict__ hb, ushort* __restrict__ rhb,
    ushort* __restrict__ WrT, ushort* __restrict__ WfT,
    ushort* __restrict__ WrsT, ushort* __restrict__ WrtT)
{
    const int bx = blockIdx.x, tid = threadIdx.x;
    if (bx < 4608) {
        const float* in = (bx < 4096) ? h : rh;
        ushort* o = (bx < 4096) ? hb : rhb;
        const int i = (bx < 4096 ? bx : bx - 4096) * 256 + tid;
        const float4 v = ((const float4*)in)[i];
        ushort4 u; u.x = f2bf(v.x); u.y = f2bf(v.y); u.z = f2bf(v.z); u.w = f2bf(v.w);
        ((ushort4*)o)[i] = u;
        return;
    }
    __shared__ float TS[64][65];
    int t = bx - 4608;
    const float* in; ushort* out; int K, tk, tn;
    if (t < 64)       { in = Wr;  out = WrT;  K = 512; tk = t & 7; tn = t >> 3; }
    else if (t < 128) { in = Wf;  out = WfT;  K = 512; t -= 64; tk = t & 7; tn = t >> 3; }
    else if (t < 136) { in = Wrs; out = WrsT; K = 64;  tk = 0; tn = t - 128; }
    else              { in = Wrt; out = WrtT; K = 64;  tk = 0; tn = t - 136; }
    const int k0 = tk * 64, n0 = tn * 64;
    const int r = tid >> 4, c4 = (tid & 15) * 4;
    #pragma unroll
    for (int p = 0; p < 4; ++p) {
        const int row = r + 16 * p;
        const float4 v = *(const float4*)(in + (size_t)(k0 + row) * 512 + n0 + c4);
        TS[row][c4] = v.x; TS[row][c4 + 1] = v.y;
        TS[row][c4 + 2] = v.z; TS[row][c4 + 3] = v.w;
    }
    __syncthreads();
    #pragma unroll
    for (int p = 0; p < 4; ++p) {
        const int nn = r + 16 * p;
        ushort4 o;
        o.x = f2bf(TS[c4 + 0][nn]); o.y = f2bf(TS[c4 + 1][nn]);
        o.z = f2bf(TS[c4 + 2][nn]); o.w = f2bf(TS[c4 + 3][nn]);
        *(ushort4*)(out + (size_t)(n0 + nn) * K + k0 + c4) = o;
    }
}

// ---------------------------------------------------------------------------
// proj (fused): grid (128,4,3). z=0: fr-projection (K=512) -> frT bf16 + sr;
// z=1: rk (K=64, xLOG2E); z=2: rq (K=64). 64x128 tile, double-buffered
// global_load_lds staging, chunk-swizzled LDS (R7-proven k-loop).
// ---------------------------------------------------------------------------
__global__ __launch_bounds__(256) void proj(
    const ushort* __restrict__ hb, const ushort* __restrict__ rhb,
    const ushort* __restrict__ WrT, const ushort* __restrict__ WrsT,
    const ushort* __restrict__ WrtT,
    ushort* __restrict__ frT, ushort* __restrict__ rkw, ushort* __restrict__ rqw,
    float* __restrict__ sred, const float* __restrict__ ar)
{
    __shared__ ushort As[2][64 * 32];
    __shared__ ushort Bs[2][128 * 32];

    const int tid = threadIdx.x;
    const int lane = tid & 63, w = tid >> 6;
    const int ln = lane & 15, quad = lane >> 4;
    const int wm = w >> 1, wn = w & 1;
    const int m0 = blockIdx.x * 64, n0 = blockIdx.y * 128;
    const int z = blockIdx.z;

    const ushort* A; const ushort* wt; ushort* co; float scl; int K;
    if (z == 0)      { A = hb;  wt = WrT;  co = frT; scl = LOG2E; K = 512; }
    else if (z == 1) { A = rhb; wt = WrsT; co = rkw; scl = LOG2E; K = 64; }
    else             { A = rhb; wt = WrtT; co = rqw; scl = 1.0f;  K = 64; }

    const int srA = tid >> 2;
    const int lchA = ((lane & 3) - (srA >> 1)) & 3;
    const ushort* AgB = A + (size_t)(m0 + srA) * K + lchA * 8;
    const int srB = w * 32 + (lane >> 2);
    const int lchB = ((lane & 3) - (srB >> 1)) & 3;
    const ushort* BgB0 = wt + (size_t)(n0 + srB) * K + lchB * 8;
    const ushort* BgB1 = BgB0 + (size_t)16 * K;
    const int aoff = tid * 8;
    const int boff = srB * 32 + (lane & 3) * 8;
    const int pc = (quad + (ln >> 1)) & 3;

    g2lds16(AgB, &As[0][aoff]);
    g2lds16(BgB0, &Bs[0][boff]);
    g2lds16(BgB1, &Bs[0][boff + 512]);

    f32x4 acc[2][4] = {};
    int buf = 0;
    for (int k0 = 0; k0 < K; k0 += 32) {
        __syncthreads();
        if (k0 + 32 < K) {
            g2lds16(AgB + k0 + 32, &As[buf ^ 1][aoff]);
            g2lds16(BgB0 + k0 + 32, &Bs[buf ^ 1][boff]);
            g2lds16(BgB1 + k0 + 32, &Bs[buf ^ 1][boff + 512]);
        }
        bf16x8 af[2], bfr[4];
        #pragma unroll
        for (int mi = 0; mi < 2; ++mi)
            af[mi] = *(const bf16x8*)&As[buf][(wm * 32 + mi * 16 + ln) * 32 + pc * 8];
        #pragma unroll
        for (int ni = 0; ni < 4; ++ni)
            bfr[ni] = *(const bf16x8*)&Bs[buf][(wn * 64 + ni * 16 + ln) * 32 + pc * 8];
        #pragma unroll
        for (int mi = 0; mi < 2; ++mi)
            #pragma unroll
            for (int ni = 0; ni < 4; ++ni)
                acc[mi][ni] = __builtin_amdgcn_mfma_f32_16x16x32_bf16(
                    af[mi], bfr[ni], acc[mi][ni], 0, 0, 0);
        buf ^= 1;
    }

    const int head = blockIdx.y * 2 + wn;
    const int b = m0 >> 11;
    const size_t bh = (size_t)b * H_ + head;
    if (z == 0) {
        // frT[b,h,d,s] + sred
        #pragma unroll
        for (int mi = 0; mi < 2; ++mi) {
            const int s = (m0 & (S_ - 1)) + wm * 32 + mi * 16 + quad * 4;
            #pragma unroll
            for (int ni = 0; ni < 4; ++ni) {
                const int d = ni * 16 + ln;
                ushort4 o;
                o.x = f2bf(acc[mi][ni][0]); o.y = f2bf(acc[mi][ni][1]);
                o.z = f2bf(acc[mi][ni][2]); o.w = f2bf(acc[mi][ni][3]);
                *(ushort4*)(co + (bh * 64 + d) * S_ + s) = o;
            }
        }
        float a4[4];
        #pragma unroll
        for (int ni = 0; ni < 4; ++ni) a4[ni] = ar[ni * 16 + ln];
        #pragma unroll
        for (int mi = 0; mi < 2; ++mi) {
            const int s = (m0 & (S_ - 1)) + wm * 32 + mi * 16 + quad * 4;
            #pragma unroll
            for (int r = 0; r < 4; ++r) {
                float v = 0.f;
                #pragma unroll
                for (int ni = 0; ni < 4; ++ni)
                    v += leaky(acc[mi][ni][r]) * a4[ni];
                #pragma unroll
                for (int off = 8; off; off >>= 1) v += __shfl_xor(v, off, 16);
                if (ln == 0) sred[bh * S_ + s + r] = v * scl;
            }
        }
    } else {
        #pragma unroll
        for (int mi = 0; mi < 2; ++mi) {
            const int s = (m0 & (S_ - 1)) + wm * 32 + mi * 16 + quad * 4;
            #pragma unroll
            for (int ni = 0; ni < 4; ++ni) {
                const int d = ni * 16 + ln;
                #pragma unroll
                for (int r = 0; r < 4; ++r)
                    co[(bh * S_ + s + r) * 64 + d] = f2bf(acc[mi][ni][r] * scl);
            }
        }
    }
}

// ---------------------------------------------------------------------------
// Flash attention, bf16 MFMA. 128 q / block = 4 waves x 32 q (2 frag-sets):
// each B-fragment read feeds 2x MFMAs (B is q-independent; R7's 4-way q-split
// re-read identical B 4x -> LDS-BW bound). Grid (16,8,4)=512, LDS 48 KB.
// Double-buffered async staging; t-loop unrolled x2 so buf is compile-time
// and all LDS addresses are hoisted base-pointers + const offsets.
// No max-subtraction (scores pre-scaled by LOG2E); sl cancels in softmax.
// ---------------------------------------------------------------------------
__global__ __launch_bounds__(256, 2) void attn_mfma(
    const ushort* __restrict__ frT, const ushort* __restrict__ rk,
    const ushort* __restrict__ rq, const float* __restrict__ sr,
    ushort* __restrict__ hsa)
{
    __shared__ ushort RQ[2][64][64];   // [t][r-granules swizzled] 16 KB
    __shared__ ushort FT[2][64][64];   // [d][t-granules swizzled] 16 KB
    __shared__ ushort PS[8][16][64];   // per-(wave,qs) P strip,   16 KB

    const int tid = threadIdx.x;
    const int w = tid >> 6;
    const int lane = tid & 63;
    const int ln = lane & 15;
    const int quad = lane >> 4;
    const int b = blockIdx.z, h = blockIdx.y, q0 = blockIdx.x * 128;
    const size_t bh = (size_t)b * H_ + h;

    // A-frags (rk): q = q0 + 32w + 16qs + ln
    bf16x8 a[2][2];
    #pragma unroll
    for (int qs = 0; qs < 2; ++qs) {
        const ushort* p = rk + ((bh * S_ + q0 + 32 * w + 16 * qs + ln) << 6);
        a[qs][0] = *(const bf16x8*)(p + quad * 8);
        a[qs][1] = *(const bf16x8*)(p + 32 + quad * 8);
    }

    const ushort* rq_g = rq + (bh * S_ << 6);
    const ushort* ft_g = frT + (size_t)bh * 64 * S_;
    const float* srp = sr + bh * S_;

    // staging: block covers tile rows 0..63 (wave w: [16w,16w+16), 2x8 rows)
    const int rl = lane >> 3;
    const int pg = lane & 7;
    const int row_b = w * 16 + rl;
    const int sgF = (pg - rl) & 7;                    // FT swizzle (g+row)&7
    const int sgR0 = (pg - 4 * w - (rl >> 2)) & 7;    // RQ swizzle (g+(row>>2))&7
    const int sgR1 = (pg - 4 * w - 2 - (rl >> 2)) & 7;

    #define STAGE(BUF, t0)                                                    \
        {                                                                     \
            g2lds16(rq_g + ((size_t)((t0) + row_b) << 6) + sgR0 * 8,          \
                    &RQ[BUF][row_b][pg * 8]);                                 \
            g2lds16(rq_g + ((size_t)((t0) + row_b + 8) << 6) + sgR1 * 8,      \
                    &RQ[BUF][row_b + 8][pg * 8]);                             \
            g2lds16(ft_g + (size_t)row_b * S_ + (t0) + sgF * 8,               \
                    &FT[BUF][row_b][pg * 8]);                                 \
            g2lds16(ft_g + (size_t)(row_b + 8) * S_ + (t0) + sgF * 8,         \
                    &FT[BUF][row_b + 8][pg * 8]);                             \
        }

    // hoisted LDS read bases (+ half*4096 selects buffer)
    const ushort* rqrA = &RQ[0][0][0] + 4 * ln * 64 + ((quad + ln) & 7) * 8;
    const ushort* rqrB = &RQ[0][0][0] + 4 * ln * 64 + ((quad + 4 + ln) & 7) * 8;
    const ushort* ftrA = &FT[0][0][0] + ln * 64 + ((quad + ln) & 7) * 8;
    const ushort* ftrB = &FT[0][0][0] + ln * 64 + ((quad + 4 + ln) & 7) * 8;
    // PS strip pointers (per qs): write offsets per r, read bases
    ushort* sb[2];
    sb[0] = &PS[w * 2][0][0]; sb[1] = &PS[w * 2 + 1][0][0];
    int wr_off[4];
    #pragma unroll
    for (int r = 0; r < 4; ++r) {
        const int prow = quad * 4 + r;
        wr_off[r] = prow * 64 + (((ln >> 1) + prow) & 7) * 8 + (ln & 1) * 4;
    }
    const int rd0 = ln * 64 + ((quad + ln) & 7) * 8;
    const int rd1 = ln * 64 + ((quad + 4 + ln) & 7) * 8;

    STAGE(0, 0)
    __syncthreads();

    float lsum[2][4] = {};
    f32x4 ctx[2][4] = {};

    for (int t0 = 0; t0 < S_; t0 += 128) {
        #pragma unroll
        for (int half = 0; half < 2; ++half) {
            const int tc = t0 + 64 * half;
            if (tc + 64 < S_) {
                if (half == 0) STAGE(1, tc + 64)
                else           STAGE(0, tc + 64)
            }
            const float4 srv = *(const float4*)(srp + tc + 4 * ln);

            // ---- QK^T: tile jb -> t = 4*ln + jb ----
            f32x4 sc[2][4];
            #pragma unroll
            for (int jb = 0; jb < 4; ++jb) {
                const bf16x8 b0 = *(const bf16x8*)(rqrA + half * 4096 + jb * 64);
                const bf16x8 b1 = *(const bf16x8*)(rqrB + half * 4096 + jb * 64);
                #pragma unroll
                for (int qs = 0; qs < 2; ++qs) {
                    f32x4 t = {0.f, 0.f, 0.f, 0.f};
                    t = __builtin_amdgcn_mfma_f32_16x16x32_bf16(a[qs][0], b0, t, 0, 0, 0);
                    t = __builtin_amdgcn_mfma_f32_16x16x32_bf16(a[qs][1], b1, t, 0, 0, 0);
                    sc[qs][jb] = t;
                }
            }

            // ---- softmax (exp2, no max) -> packed b64 P writes ----
            #pragma unroll
            for (int qs = 0; qs < 2; ++qs)
                #pragma unroll
                for (int r = 0; r < 4; ++r) {
                    const float p0 = __builtin_amdgcn_exp2f(sc[qs][0][r] + srv.x);
                    const float p1 = __builtin_amdgcn_exp2f(sc[qs][1][r] + srv.y);
                    const float p2 = __builtin_amdgcn_exp2f(sc[qs][2][r] + srv.z);
                    const float p3 = __builtin_amdgcn_exp2f(sc[qs][3][r] + srv.w);
                    lsum[qs][r] += (p0 + p1) + (p2 + p3);
                    const unsigned lo = (fbits(p0) >> 16) | (fbits(p1) & 0xffff0000u);
                    const unsigned hi = (fbits(p2) >> 16) | (fbits(p3) & 0xffff0000u);
                    *(uint2*)(sb[qs] + wr_off[r]) = make_uint2(lo, hi);
                }

            // ---- PV: A = P strips, B = FT[d][t] ----
            const bf16x8 pa00 = *(const bf16x8*)(sb[0] + rd0);
            const bf16x8 pa01 = *(const bf16x8*)(sb[0] + rd1);
            const bf16x8 pa10 = *(const bf16x8*)(sb[1] + rd0);
            const bf16x8 pa11 = *(const bf16x8*)(sb[1] + rd1);
            #pragma unroll
            for (int jb = 0; jb < 4; ++jb) {
                const bf16x8 fb0 = *(const bf16x8*)(ftrA + half * 4096 + jb * 1024);
                const bf16x8 fb1 = *(const bf16x8*)(ftrB + half * 4096 + jb * 1024);
                ctx[0][jb] = __builtin_amdgcn_mfma_f32_16x16x32_bf16(pa00, fb0, ctx[0][jb], 0, 0, 0);
                ctx[0][jb] = __builtin_amdgcn_mfma_f32_16x16x32_bf16(pa01, fb1, ctx[0][jb], 0, 0, 0);
                ctx[1][jb] = __builtin_amdgcn_mfma_f32_16x16x32_bf16(pa10, fb0, ctx[1][jb], 0, 0, 0);
                ctx[1][jb] = __builtin_amdgcn_mfma_f32_16x16x32_bf16(pa11, fb1, ctx[1][jb], 0, 0, 0);
            }

            __syncthreads();   // drains prefetch + guards buffer reuse
        }
    }

    #pragma unroll
    for (int qs = 0; qs < 2; ++qs)
        #pragma unroll
        for (int r = 0; r < 4; ++r) {
            float l = lsum[qs][r];
            #pragma unroll
            for (int off = 8; off; off >>= 1) l += __shfl_xor(l, off, 16);
            const float inv = 1.f / l;
            const int q = q0 + 32 * w + 16 * qs + quad * 4 + r;
            ushort* orow = hsa + (size_t)(b * S_ + q) * D_ + h * 64;
            #pragma unroll
            for (int jb = 0; jb < 4; ++jb)
                orow[16 * jb + ln] = f2bf(ctx[qs][jb][r] * inv);
        }
}

// ---------------------------------------------------------------------------
// final projection GEMM (fp32 out), double-buffered (R7-proven)
// ---------------------------------------------------------------------------
__global__ __launch_bounds__(256) void gemm_out(
    const ushort* __restrict__ A, const ushort* __restrict__ WT,
    float* __restrict__ C)
{
    __shared__ ushort As[2][64 * 32];
    __shared__ ushort Bs[2][128 * 32];

    const int tid = threadIdx.x;
    const int lane = tid & 63, w = tid >> 6;
    const int ln = lane & 15, quad = lane >> 4;
    const int wm = w >> 1, wn = w & 1;
    const int m0 = blockIdx.x * 64, n0 = blockIdx.y * 128;
    const int K = 512;

    const int srA = tid >> 2;
    const int lchA = ((lane & 3) - (srA >> 1)) & 3;
    const ushort* AgB = A + (size_t)(m0 + srA) * K + lchA * 8;
    const int srB = w * 32 + (lane >> 2);
    const int lchB = ((lane & 3) - (srB >> 1)) & 3;
    const ushort* BgB0 = WT + (size_t)(n0 + srB) * K + lchB * 8;
    const ushort* BgB1 = BgB0 + (size_t)16 * K;
    const int aoff = tid * 8;
    const int boff = srB * 32 + (lane & 3) * 8;
    const int pc = (quad + (ln >> 1)) & 3;

    g2lds16(AgB, &As[0][aoff]);
    g2lds16(BgB0, &Bs[0][boff]);
    g2lds16(BgB1, &Bs[0][boff + 512]);

    f32x4 acc[2][4] = {};
    int buf = 0;
    for (int k0 = 0; k0 < K; k0 += 32) {
        __syncthreads();
        if (k0 + 32 < K) {
            g2lds16(AgB + k0 + 32, &As[buf ^ 1][aoff]);
            g2lds16(BgB0 + k0 + 32, &Bs[buf ^ 1][boff]);
            g2lds16(BgB1 + k0 + 32, &Bs[buf ^ 1][boff + 512]);
        }
        bf16x8 af[2], bfr[4];
        #pragma unroll
        for (int mi = 0; mi < 2; ++mi)
            af[mi] = *(const bf16x8*)&As[buf][(wm * 32 + mi * 16 + ln) * 32 + pc * 8];
        #pragma unroll
        for (int ni = 0; ni < 4; ++ni)
            bfr[ni] = *(const bf16x8*)&Bs[buf][(wn * 64 + ni * 16 + ln) * 32 + pc * 8];
        #pragma unroll
        for (int mi = 0; mi < 2; ++mi)
            #pragma unroll
            for (int ni = 0; ni < 4; ++ni)
                acc[mi][ni] = __builtin_amdgcn_mfma_f32_16x16x32_bf16(
                    af[mi], bfr[ni], acc[mi][ni], 0, 0, 0);
        buf ^= 1;
    }

    #pragma unroll
    for (int mi = 0; mi < 2; ++mi) {
        const int row = m0 + wm * 32 + mi * 16 + quad * 4;
        #pragma unroll
        for (int ni = 0; ni < 4; ++ni) {
            const int col = n0 + wn * 64 + ni * 16 + ln;
            #pragma unroll
            for (int r = 0; r < 4; ++r)
                C[(size_t)(row + r) * 512 + col] = acc[mi][ni][r];
        }
    }
}

// ---------------------------------------------------------------------------
// LayerNorm(h + fh) * g + b
// ---------------------------------------------------------------------------
__global__ __launch_bounds__(256) void ln_kernel(
    const float* __restrict__ h, const float* __restrict__ fh,
    const float* __restrict__ g, const float* __restrict__ bb,
    float* __restrict__ out)
{
    const int row = blockIdx.x, tid = threadIdx.x;
    const float* hp = h + (size_t)row * 512;
    const float* fp = fh + (size_t)row * 512;
    const float x0 = hp[tid] + fp[tid];
    const float x1 = hp[tid + 256] + fp[tid + 256];
    __shared__ float red[4];

    float s = x0 + x1;
    #pragma unroll
    for (int off = 32; off; off >>= 1) s += __shfl_xor(s, off, 64);
    if ((tid & 63) == 0) red[tid >> 6] = s;
    __syncthreads();
    const float mu = (red[0] + red[1] + red[2] + red[3]) * (1.f / 512.f);

    const float d0 = x0 - mu, d1 = x1 - mu;
    float v = d0 * d0 + d1 * d1;
    #pragma unroll
    for (int off = 32; off; off >>= 1) v += __shfl_xor(v, off, 64);
    __syncthreads();
    if ((tid & 63) == 0) red[tid >> 6] = v;
    __syncthreads();
    const float var = (red[0] + red[1] + red[2] + red[3]) * (1.f / 512.f);
    const float inv = rsqrtf(var + LN_EPS);

    out[(size_t)row * 512 + tid] = d0 * inv * g[tid] + bb[tid];
    out[(size_t)row * 512 + tid + 256] = d1 * inv * g[tid + 256] + bb[tid + 256];
}

// ---------------------------------------------------------------------------
extern "C" void kernel_launch(void* const* d_in, const int* in_sizes, int n_in,
                              void* d_out, int out_size, void* d_ws, size_t ws_size,
                              hipStream_t stream)
{
    const float* h   = (const float*)d_in[0];
    const float* rh  = (const float*)d_in[1];
    // d_in[2] = Wl, d_in[4] = al : unused — sl cancels in softmax
    const float* Wr  = (const float*)d_in[3];
    const float* ar  = (const float*)d_in[5];
    const float* Wrs = (const float*)d_in[6];
    const float* Wrt = (const float*)d_in[7];
    const float* Wf  = (const float*)d_in[8];
    const float* lng = (const float*)d_in[9];
    const float* lnb = (const float*)d_in[10];
    float* out = (float*)d_out;
    char* wsb  = (char*)d_ws;

    const size_t MB = (size_t)1 << 20;
    ushort* hb   = (ushort*)(wsb);               //  8 MB
    ushort* rhb  = (ushort*)(wsb + 8 * MB);      //  1 MB
    ushort* WrT  = (ushort*)(wsb + 9 * MB);      // .5 MB
    ushort* WfT  = (ushort*)(wsb + 9 * MB + 512 * 1024);
    ushort* WrsT = (ushort*)(wsb + 10 * MB);     // 64 KB
    ushort* WrtT = (ushort*)(wsb + 10 * MB + 64 * 1024);
    ushort* frT  = (ushort*)(wsb + 11 * MB);     //  8 MB  [B,H,64,S]
    ushort* rkw  = (ushort*)(wsb + 19 * MB);     //  8 MB  [B,H,S,64]
    ushort* rqw  = (ushort*)(wsb + 27 * MB);     //  8 MB  [B,H,S,64]
    float*  sr   = (float*) (wsb + 35 * MB);     // .25MB  [B,H,S]
    ushort* hsab = (ushort*)(wsb + 36 * MB);     //  8 MB  [B,S,512] bf16
    float*  fh   = (float*) (wsb + 44 * MB);     // 16 MB  [B,S,512] f32

    dim3 blk(256);
    prep<<<dim3(4752), blk, 0, stream>>>(h, rh, Wr, Wf, Wrs, Wrt,
                                         hb, rhb, WrT, WfT, WrsT, WrtT);
    // fr projection + both relation projections, one dispatch (z = 3)
    proj<<<dim3(128, 4, 3), blk, 0, stream>>>(hb, rhb, WrT, WrsT, WrtT,
                                              frT, rkw, rqw, sr, ar);
    // attention -> hsa bf16 (128 q / block, 32 q / wave)
    attn_mfma<<<dim3(S_ / 128, H_, B_), blk, 0, stream>>>(frT, rkw, rqw, sr, hsab);
    // final projection -> fh f32
    gemm_out<<<dim3(128, 4), blk, 0, stream>>>(hsab, WfT, fh);
    // residual + layernorm
    ln_kernel<<<dim3(B_ * S_), blk, 0, stream>>>(h, fh, lng, lnb, out);
}